// Round 12
// baseline (76.236 us; speedup 1.0000x reference)
//
#include <hip/hip_runtime.h>
#include <hip/hip_bf16.h>
#include <stdint.h>

#define BB    4
#define NQ    8192
#define NS    4096
#define FDIM  256
#define KNN   8
#define NT    512                // 8 waves: quarter (w&3) x query-group (w>>2)
#define QPB   32                 // queries per block (2 groups of 16)
#define CAP   192                // candidate capacity (E=64, sigma~23 -> 5.5 sigma)
#define MARGIN 0.0035f           // > 2x bf16-split error bound (~1.1e-3)
#define NSQ   (NS / 4)           // sensors per quarter = 1024
#define QTILES (NSQ / 16)        // 64 MFMA tiles per quarter
#define SSTRIDE 8                // sample every 8th tile (512 pooled samples/query)

typedef unsigned long long u64;
typedef __attribute__((ext_vector_type(8))) short bf16x8;   // 8 bf16 (4 VGPR)
typedef __attribute__((ext_vector_type(4))) float f32x4;

__device__ __forceinline__ float med3(float a, float b, float c) {
    return __builtin_amdgcn_fmed3f(a, b, c);
}
__device__ __forceinline__ unsigned short f2bf(float v) {
    __hip_bfloat16 h = __float2bfloat16(v);
    return *reinterpret_cast<unsigned short*>(&h);
}
__device__ __forceinline__ float bf2f(unsigned short u) {
    __hip_bfloat16 h;
    *reinterpret_cast<unsigned short*>(&h) = u;
    return __bfloat162float(h);
}

// ---------------- d_ws layout ----------------
// tbl  : [NS][16] bf16 @ 0       (128 KB)  MFMA K-vectors [layout verified r8]
// tblf : [NS] float4  @ 131072   (64 KB)   (-2x,-2y,-2z,s^2) f32 for refine
#define WS_TBLF  131072
#define WS_NEED  196608

// ============ build: bf16 K-vector table + f32 refine table ============
// k: 0:s2_hi 1:s2_lo 2:mx_hi 3:mx_lo 4:mx_hi 5:my_hi 6:my_lo 7:my_hi
//    8:mz_hi 9:mz_lo 10:mz_hi 11..15:0        (m* = -2*coord)
__global__ __launch_bounds__(256) void build_tbl(const float* __restrict__ sc,
                                                 unsigned short* __restrict__ tbl,
                                                 float4* __restrict__ tblf) {
    const int s = blockIdx.x * 256 + threadIdx.x;
    if (s >= NS) return;
    const float sx = sc[3*s], sy = sc[3*s+1], sz = sc[3*s+2];
    const float s2 = __fmaf_rn(sx, sx, __fmaf_rn(sy, sy, __fmul_rn(sz, sz)));
    const float mx = -2.0f*sx, my = -2.0f*sy, mz = -2.0f*sz;
    unsigned short e[16];
    #pragma unroll
    for (int j = 0; j < 16; ++j) e[j] = 0;
    unsigned short h, l;
    h = f2bf(s2); l = f2bf(s2 - bf2f(h)); e[0] = h; e[1] = l;
    h = f2bf(mx); l = f2bf(mx - bf2f(h)); e[2] = h; e[3] = l; e[4]  = h;
    h = f2bf(my); l = f2bf(my - bf2f(h)); e[5] = h; e[6] = l; e[7]  = h;
    h = f2bf(mz); l = f2bf(mz - bf2f(h)); e[8] = h; e[9] = l; e[10] = h;
    #pragma unroll
    for (int j = 0; j < 16; ++j) tbl[s * 16 + j] = e[j];
    tblf[s] = make_float4(mx, my, mz, s2);
}

// ===== main: pooled-sample threshold -> MFMA sweep -> parallel exact refine =====
__global__ __launch_bounds__(NT, 8) void knn_mfma(
    const float* __restrict__ qc, const float* __restrict__ sf,
    const unsigned short* __restrict__ tbl, const float4* __restrict__ tblf,
    float* __restrict__ out)
{
    __shared__ unsigned short s_qvec[QPB][32];   // query K-vectors (k11..31 zero)
    __shared__ float4 s_q[QPB];                  // qx,qy,qz,q2 (f32, refine)
    __shared__ float  s_samp[QPB][4][KNN];       // per-quarter sample-top-8 (4 KB)
    __shared__ float  s_thrq[QPB];               // pooled threshold (+MARGIN)
    __shared__ int    s_cnt[QPB];
    __shared__ int    s_cand[QPB][CAP];          // 24 KB
    __shared__ int    s_idx[QPB][KNN];
    __shared__ float  s_w[QPB][KNN];

    const int tid = threadIdx.x;

    // XCD swizzle: batch b -> XCD pair {2b,2b+1}; bijective over 1024 blocks.
    const int p   = blockIdx.x;
    const int b   = (p >> 1) & 3;
    const int sub = ((p >> 3) << 1) | (p & 1);   // 0..255
    const int q0  = b * NQ + sub * QPB;

    // ---- stage query K-vectors + f32 coords ----
    if (tid < QPB) {
        const float* qp = qc + (size_t)(q0 + tid) * 3;
        const float qx = qp[0], qy = qp[1], qz = qp[2];
        const float q2 = __fmaf_rn(qx, qx, __fmaf_rn(qy, qy, __fmul_rn(qz, qz)));
        s_q[tid] = make_float4(qx, qy, qz, q2);
        #pragma unroll
        for (int j = 11; j < 32; ++j) s_qvec[tid][j] = 0;
        const unsigned short one = f2bf(1.0f);
        unsigned short h, l;
        s_qvec[tid][0] = one; s_qvec[tid][1] = one;
        h = f2bf(qx); l = f2bf(qx - bf2f(h));
        s_qvec[tid][2] = h; s_qvec[tid][3] = h; s_qvec[tid][4]  = l;
        h = f2bf(qy); l = f2bf(qy - bf2f(h));
        s_qvec[tid][5] = h; s_qvec[tid][6] = h; s_qvec[tid][7]  = l;
        h = f2bf(qz); l = f2bf(qz - bf2f(h));
        s_qvec[tid][8] = h; s_qvec[tid][9] = h; s_qvec[tid][10] = l;
        s_cnt[tid] = 0;
    }
    __syncthreads();

    const int wid  = tid >> 6;        // wave 0..7
    const int lane = tid & 63;
    const int qtr  = wid & 3;         // sensor quarter
    const int qg   = wid >> 2;        // query group 0..1
    const int kc   = lane >> 4;       // k-chunk 0..3
    const int qn   = lane & 15;       // query col within tile
    const int qloc = qg * 16 + qn;    // query id in block
    const int sbase = qtr * NSQ;

    // B fragment: col = lane&15 (query), k = 8*(lane>>4)+i  [verified r8]
    const bf16x8 bfrag = *reinterpret_cast<const bf16x8*>(&s_qvec[qloc][kc * 8]);
    const f32x4 zero = {0.f, 0.f, 0.f, 0.f};

    // A fragment source: row = lane&15 (sensor in tile); k-chunks 0..1 real
    const unsigned short* abase =
        tbl + ((size_t)(sbase + qn) * 16 + (kc & 1) * 8);

    // ---- pass S: per-lane top-8 over SAMPLED tiles (every 8th) ----
    float kd[KNN];
    #pragma unroll
    for (int j = 0; j < KNN; ++j) kd[j] = 3.4e38f;

    #pragma unroll 2
    for (int ts = 0; ts < QTILES / SSTRIDE; ++ts) {   // 8 tiles = 128 sensors
        const int t = ts * SSTRIDE;
        bf16x8 a = {};
        if (kc < 2) a = *reinterpret_cast<const bf16x8*>(abase + t * 256);
        const f32x4 d = __builtin_amdgcn_mfma_f32_16x16x32_bf16(a, bfrag, zero, 0, 0, 0);
        #pragma unroll
        for (int r = 0; r < 4; ++r) {
            const float x = d[r];
            if (x < kd[KNN-1]) {     // insert is a no-op unless x beats the 8th
                const float nk0 = fminf(kd[0], x);
                #pragma unroll
                for (int j = KNN - 1; j >= 1; --j) kd[j] = med3(kd[j-1], kd[j], x);
                kd[0] = nk0;
            }
        }
    }

    // ---- tournament over 4 k-lanes: record all 8 winners (quarter sample-top8) ----
    float smp[KNN];
    #pragma unroll
    for (int r = 0; r < KNN; ++r) {
        float m = kd[0];
        m = fminf(m, __shfl_xor(m, 16, 64));
        m = fminf(m, __shfl_xor(m, 32, 64));
        const bool pop = (kd[0] == m);   // tie over-pop only RAISES values (safe)
        #pragma unroll
        for (int j = 0; j < KNN - 1; ++j) kd[j] = pop ? kd[j+1] : kd[j];
        kd[KNN-1] = pop ? 3.4e38f : kd[KNN-1];
        smp[r] = m;
    }
    if (kc == 0) {
        #pragma unroll
        for (int r = 0; r < KNN; ++r) s_samp[qloc][qtr][r] = smp[r];
    }
    __syncthreads();

    // ---- pool 4x8 quarter lists -> pooled sample-8th (rank ~64 of 4096) ----
    if (tid < QPB) {
        float pk[KNN];
        #pragma unroll
        for (int j = 0; j < KNN; ++j) pk[j] = 3.4e38f;
        #pragma unroll
        for (int w4 = 0; w4 < 4; ++w4) {
            #pragma unroll
            for (int r = 0; r < KNN; ++r) {
                const float x = s_samp[tid][w4][r];
                const float nk0 = fminf(pk[0], x);
                #pragma unroll
                for (int j = KNN - 1; j >= 1; --j) pk[j] = med3(pk[j-1], pk[j], x);
                pk[0] = nk0;
            }
        }
        s_thrq[tid] = pk[KNN - 1] + MARGIN;   // superset threshold (proof as r8)
    }
    __syncthreads();

    const float thr_eff = s_thrq[qloc];

    // ---- pass C: full MFMA sweep; batched-atomic candidate collection ----
    #pragma unroll 2
    for (int t = 0; t < QTILES; ++t) {
        bf16x8 a = {};
        if (kc < 2) a = *reinterpret_cast<const bf16x8*>(abase + t * 256);
        const f32x4 d = __builtin_amdgcn_mfma_f32_16x16x32_bf16(a, bfrag, zero, 0, 0, 0);
        const bool h0 = d[0] <= thr_eff, h1 = d[1] <= thr_eff;
        const bool h2 = d[2] <= thr_eff, h3 = d[3] <= thr_eff;
        const int n = (int)h0 + (int)h1 + (int)h2 + (int)h3;
        if (n) {
            int pos = atomicAdd(&s_cnt[qloc], n);          // one atomic per lane
            const int sid0 = sbase + t * 16 + kc * 4;
            if (h0) { if (pos < CAP) s_cand[qloc][pos] = sid0;     ++pos; }
            if (h1) { if (pos < CAP) s_cand[qloc][pos] = sid0 + 1; ++pos; }
            if (h2) { if (pos < CAP) s_cand[qloc][pos] = sid0 + 2; ++pos; }
            if (h3) { if (pos < CAP) s_cand[qloc][pos] = sid0 + 3; }
        }
    }
    __syncthreads();

    // ---- parallel exact refine: wave wid -> queries wid*4..+3 ----
    // 16 lanes per query split candidates; per-lane sorted u64 top-8;
    // 16-lane u64 pop-tournament -> exact top-8 (keys unique -> one pop).
    {
        const int sg = lane >> 4;            // subgroup 0..3
        const int li = lane & 15;            // lane within subgroup
        const int qr = wid * 4 + sg;         // query refined by this subgroup (0..31)
        const int cnt0 = s_cnt[qr];
        const float qx = s_q[qr].x, qy = s_q[qr].y, qz = s_q[qr].z, q2 = s_q[qr].w;

        u64 kb[KNN];
        #pragma unroll
        for (int j = 0; j < KNN; ++j) kb[j] = ~0ull;

        if (cnt0 <= CAP) {
            for (int i = li; i < cnt0; i += 16) {
                const int sid = s_cand[qr][i];
                const float4 m = tblf[sid];
                const float x  = __fmaf_rn(qx, m.x,
                                 __fmaf_rn(qy, m.y, __fmaf_rn(qz, m.z, m.w)));
                const float d2 = fmaxf(__fadd_rn(x, q2), 0.0f);
                u64 cur = ((u64)__float_as_uint(d2) << 32) | (unsigned)sid;
                #pragma unroll
                for (int j = 0; j < KNN; ++j) {
                    const u64 lo = kb[j] < cur ? kb[j] : cur;
                    const u64 hi = kb[j] < cur ? cur : kb[j];
                    kb[j] = lo; cur = hi;
                }
            }
        } else {
            // safety net (>=5.5 sigma): exact full scan, split over 16 lanes
            for (int sid = li; sid < NS; sid += 16) {
                const float4 m = tblf[sid];
                const float x  = __fmaf_rn(qx, m.x,
                                 __fmaf_rn(qy, m.y, __fmaf_rn(qz, m.z, m.w)));
                const float d2 = fmaxf(__fadd_rn(x, q2), 0.0f);
                u64 cur = ((u64)__float_as_uint(d2) << 32) | (unsigned)sid;
                #pragma unroll
                for (int j = 0; j < KNN; ++j) {
                    const u64 lo = kb[j] < cur ? kb[j] : cur;
                    const u64 hi = kb[j] < cur ? cur : kb[j];
                    kb[j] = lo; cur = hi;
                }
            }
        }

        u64 sel = ~0ull;
        #pragma unroll
        for (int r = 0; r < KNN; ++r) {
            u64 v = kb[0];
            #pragma unroll
            for (int m = 1; m <= 8; m <<= 1) {
                const u64 o = __shfl_xor(v, m, 64);   // stays within 16-lane group
                v = o < v ? o : v;
            }
            const bool pop = (kb[0] == v);
            #pragma unroll
            for (int j = 0; j < KNN - 1; ++j) kb[j] = pop ? kb[j+1] : kb[j];
            kb[KNN-1] = pop ? ~0ull : kb[KNN-1];
            if (li == r) sel = v;
        }

        // weights on lanes 0..7 of each subgroup (xor 1,2,4 stays within 0..7)
        const float d2v = __uint_as_float((unsigned)(sel >> 32));
        const int   idx = (int)(unsigned)(sel & 0xFFFFFFFFu);
        const float w   = 1.0f / (sqrtf(d2v) + 1e-8f);
        float ws = w;
        ws += __shfl_xor(ws, 1, 64);
        ws += __shfl_xor(ws, 2, 64);
        ws += __shfl_xor(ws, 4, 64);
        if (li < KNN) {
            s_idx[qr][li] = idx;
            s_w[qr][li]   = w / ws;
        }
    }
    __syncthreads();

    // ---- gather: wave wid -> queries wid*4..+3; 64 lanes x float4 ----
    const float* fb = sf + (size_t)b * NS * FDIM;
    #pragma unroll 1
    for (int jq = 0; jq < QPB / 8; ++jq) {
        const int ql = wid * (QPB / 8) + jq;
        float4 acc = {0.f, 0.f, 0.f, 0.f};
        #pragma unroll
        for (int kk = 0; kk < KNN; ++kk) {
            const int   sid = s_idx[ql][kk];
            const float wk  = s_w[ql][kk];
            const float4 v = ((const float4*)(fb + (size_t)sid * FDIM))[lane];
            acc.x += wk * v.x; acc.y += wk * v.y;
            acc.z += wk * v.z; acc.w += wk * v.w;
        }
        ((float4*)(out + (size_t)(q0 + ql) * FDIM))[lane] = acc;
    }
}

// ================= fallback (round-6 kernel) if workspace too small =================
#define FG    16
#define FQL   2
#define FNT   512
#define FGRP  (FNT / FG)
#define FQPB  (FGRP * FQL)
#define FSCAN (NS / FG)
#define FCAP  16

#define FKEYX(m, qq) __fmaf_rn(fqx[qq], (m).x, \
                     __fmaf_rn(fqy[qq], (m).y, \
                     __fmaf_rn(fqz[qq], (m).z, (m).w)))

__global__ __launch_bounds__(FNT, 4) void idw_fallback(
    const float* __restrict__ qc, const float* __restrict__ sc,
    const float* __restrict__ sf, float* __restrict__ out)
{
    __shared__ float4 s_m[NS];
    __shared__ u64    s_items[FQPB * FCAP];
    __shared__ int    s_cnt[FQPB];
    __shared__ int    s_idx[FQPB * KNN];
    __shared__ float  s_w[FQPB * KNN];

    const int tid = threadIdx.x;
    const int p   = blockIdx.x;
    const int b   = (p >> 1) & 3;
    const int sub = ((p >> 3) << 1) | (p & 1);
    const int q0  = b * NQ + sub * FQPB;

    for (int s = tid; s < NS; s += FNT) {
        const float sx = sc[3*s+0], sy = sc[3*s+1], sz = sc[3*s+2];
        const float s2 = __fmaf_rn(sx, sx, __fmaf_rn(sy, sy, __fmul_rn(sz, sz)));
        s_m[s] = make_float4(-2.0f*sx, -2.0f*sy, -2.0f*sz, s2);
    }
    if (tid < FQPB) s_cnt[tid] = 0;
    __syncthreads();

    const int g = tid >> 4, l = tid & 15;
    float fqx[FQL], fqy[FQL], fqz[FQL], fq2[FQL];
    #pragma unroll
    for (int qq = 0; qq < FQL; ++qq) {
        const float* qp = qc + (size_t)(q0 + g * FQL + qq) * 3;
        fqx[qq] = qp[0]; fqy[qq] = qp[1]; fqz[qq] = qp[2];
        fq2[qq] = __fmaf_rn(fqx[qq], fqx[qq],
                  __fmaf_rn(fqy[qq], fqy[qq], __fmul_rn(fqz[qq], fqz[qq])));
    }

    float kd[FQL][KNN];
    #pragma unroll
    for (int qq = 0; qq < FQL; ++qq)
        #pragma unroll
        for (int j = 0; j < KNN; ++j) kd[qq][j] = 3.4e38f;

    #pragma unroll 2
    for (int t = 0; t < FSCAN; ++t) {
        const float4 m = s_m[t * FG + l];
        #pragma unroll
        for (int qq = 0; qq < FQL; ++qq) {
            const float x = FKEYX(m, qq);
            const float nk0 = fminf(kd[qq][0], x);
            #pragma unroll
            for (int j = KNN - 1; j >= 1; --j)
                kd[qq][j] = med3(kd[qq][j-1], kd[qq][j], x);
            kd[qq][0] = nk0;
        }
    }

    float thr[FQL];
    #pragma unroll
    for (int qq = 0; qq < FQL; ++qq) {
        float thv = 3.4e38f;
        #pragma unroll
        for (int r = 0; r < KNN; ++r) {
            float m = kd[qq][0];
            m = fminf(m, __shfl_xor(m, 1, 64));
            m = fminf(m, __shfl_xor(m, 2, 64));
            m = fminf(m, __shfl_xor(m, 4, 64));
            m = fminf(m, __shfl_xor(m, 8, 64));
            const bool pop = (kd[qq][0] == m);
            #pragma unroll
            for (int j = 0; j < KNN - 1; ++j) kd[qq][j] = pop ? kd[qq][j+1] : kd[qq][j];
            kd[qq][KNN-1] = pop ? 3.4e38f : kd[qq][KNN-1];
            thv = m;
        }
        thr[qq] = thv;
    }

    #pragma unroll 2
    for (int t = 0; t < FSCAN; ++t) {
        const int s = t * FG + l;
        const float4 m = s_m[s];
        #pragma unroll
        for (int qq = 0; qq < FQL; ++qq) {
            const float x = FKEYX(m, qq);
            if (x <= thr[qq]) {
                const float dc = fmaxf(__fadd_rn(x, fq2[qq]), 0.0f);
                const u64 key = ((u64)__float_as_uint(dc) << 32) | (unsigned)s;
                const int qid = g * FQL + qq;
                const int pos = atomicAdd(&s_cnt[qid], 1);
                if (pos < FCAP) s_items[qid * FCAP + pos] = key;
            }
        }
    }
    __syncthreads();

    if (l < FQL) {
        const int qid = g * FQL + l;
        int cnt = s_cnt[qid];
        if (cnt > KNN) {
            cnt = cnt < FCAP ? cnt : FCAP;
            u64 best[KNN];
            #pragma unroll
            for (int j = 0; j < KNN; ++j) best[j] = ~0ull;
            for (int i = 0; i < cnt; ++i) {
                u64 cur = s_items[qid * FCAP + i];
                #pragma unroll
                for (int j = 0; j < KNN; ++j) {
                    const u64 lo = best[j] < cur ? best[j] : cur;
                    const u64 hi = best[j] < cur ? cur : best[j];
                    best[j] = lo; cur = hi;
                }
            }
            #pragma unroll
            for (int j = 0; j < KNN; ++j) s_items[qid * FCAP + j] = best[j];
        }
    }
    __syncthreads();

    {
        const int qq  = l >> 3;
        const int k   = l & 7;
        const int qid = g * FQL + qq;
        const u64 key = s_items[qid * FCAP + k];
        const float d2v = __uint_as_float((unsigned)(key >> 32));
        const int   idx = (int)(unsigned)(key & 0xFFFFFFFFu);
        const float w   = 1.0f / (sqrtf(d2v) + 1e-8f);
        float ws = w;
        ws += __shfl_xor(ws, 1, 64);
        ws += __shfl_xor(ws, 2, 64);
        ws += __shfl_xor(ws, 4, 64);
        s_idx[qid * KNN + k] = idx;
        s_w  [qid * KNN + k] = w / ws;
    }
    __syncthreads();

    const int wave = tid >> 6, lane = tid & 63;
    const float* fb = sf + (size_t)b * NS * FDIM;
    #pragma unroll 1
    for (int j = 0; j < FQPB / 8; ++j) {
        const int ql = wave * (FQPB / 8) + j;
        float4 acc = {0.f, 0.f, 0.f, 0.f};
        #pragma unroll
        for (int kk = 0; kk < KNN; ++kk) {
            const int   sid = s_idx[ql * KNN + kk];
            const float wk  = s_w  [ql * KNN + kk];
            const float4 v = ((const float4*)(fb + (size_t)sid * FDIM))[lane];
            acc.x += wk * v.x; acc.y += wk * v.y;
            acc.z += wk * v.z; acc.w += wk * v.w;
        }
        ((float4*)(out + (size_t)(q0 + ql) * FDIM))[lane] = acc;
    }
}

extern "C" void kernel_launch(void* const* d_in, const int* in_sizes, int n_in,
                              void* d_out, int out_size, void* d_ws, size_t ws_size,
                              hipStream_t stream) {
    const float* qc = (const float*)d_in[0];   // query_coords  (4,8192,3)
    const float* sc = (const float*)d_in[1];   // sensor_coords (4096,3)
    const float* sf = (const float*)d_in[2];   // sensor_features (4,4096,256)
    float* out = (float*)d_out;                // (4,8192,256)

    if (ws_size >= (size_t)WS_NEED) {
        unsigned short* tbl  = (unsigned short*)d_ws;
        float4*         tblf = (float4*)((char*)d_ws + WS_TBLF);
        build_tbl<<<NS / 256, 256, 0, stream>>>(sc, tbl, tblf);
        knn_mfma<<<(BB * NQ) / QPB, NT, 0, stream>>>(qc, sf, tbl, tblf, out);
    } else {
        idw_fallback<<<(BB * NQ) / FQPB, FNT, 0, stream>>>(qc, sc, sf, out);
    }
}

// Round 13
// 69.655 us; speedup vs baseline: 1.0945x; 1.0945x over previous
//
#include <hip/hip_runtime.h>
#include <hip/hip_bf16.h>
#include <stdint.h>

#define BB    4
#define NQ    8192
#define NS    4096
#define FDIM  256
#define KNN   8
#define NT    512                // 8 waves; wave w owns tiles [16w,16w+16)
#define QPB   32                 // queries per block (one 32-col MFMA B set)
#define CAP   192                // candidate capacity (E=64, sigma~23 -> 5.5 sigma)
#define MARGIN 0.0035f           // > 2x bf16-split error bound (~1.1e-3)
#define NTILES 128               // NS/32 total 32-sensor tiles
#define TPW   16                 // tiles per wave

typedef unsigned long long u64;
typedef __attribute__((ext_vector_type(8)))  short bf16x8;   // 8 bf16 (4 VGPR)
typedef __attribute__((ext_vector_type(16))) float f32x16;   // 32x32 C/D

__device__ __forceinline__ float med3(float a, float b, float c) {
    return __builtin_amdgcn_fmed3f(a, b, c);
}
__device__ __forceinline__ unsigned short f2bf(float v) {
    __hip_bfloat16 h = __float2bfloat16(v);
    return *reinterpret_cast<unsigned short*>(&h);
}
__device__ __forceinline__ float bf2f(unsigned short u) {
    __hip_bfloat16 h;
    *reinterpret_cast<unsigned short*>(&h) = u;
    return __bfloat162float(h);
}

// ---------------- d_ws layout ----------------
// tbl  : [NS][16] bf16 @ 0       (128 KB)  K=16 vectors (11 slots used)
// tblf : [NS] float4  @ 131072   (64 KB)   (-2x,-2y,-2z,s^2) f32 for refine
#define WS_TBLF  131072
#define WS_NEED  196608

// ============ build: bf16 K-vector table + f32 refine table ============
// k: 0:s2_hi 1:s2_lo 2:mx_hi 3:mx_lo 4:mx_hi 5:my_hi 6:my_lo 7:my_hi
//    8:mz_hi 9:mz_lo 10:mz_hi 11..15:0        (m* = -2*coord)
__global__ __launch_bounds__(256) void build_tbl(const float* __restrict__ sc,
                                                 unsigned short* __restrict__ tbl,
                                                 float4* __restrict__ tblf) {
    const int s = blockIdx.x * 256 + threadIdx.x;
    if (s >= NS) return;
    const float sx = sc[3*s], sy = sc[3*s+1], sz = sc[3*s+2];
    const float s2 = __fmaf_rn(sx, sx, __fmaf_rn(sy, sy, __fmul_rn(sz, sz)));
    const float mx = -2.0f*sx, my = -2.0f*sy, mz = -2.0f*sz;
    unsigned short e[16];
    #pragma unroll
    for (int j = 0; j < 16; ++j) e[j] = 0;
    unsigned short h, l;
    h = f2bf(s2); l = f2bf(s2 - bf2f(h)); e[0] = h; e[1] = l;
    h = f2bf(mx); l = f2bf(mx - bf2f(h)); e[2] = h; e[3] = l; e[4]  = h;
    h = f2bf(my); l = f2bf(my - bf2f(h)); e[5] = h; e[6] = l; e[7]  = h;
    h = f2bf(mz); l = f2bf(mz - bf2f(h)); e[8] = h; e[9] = l; e[10] = h;
    #pragma unroll
    for (int j = 0; j < 16; ++j) tbl[s * 16 + j] = e[j];
    tblf[s] = make_float4(mx, my, mz, s2);
}

// ===== main: pooled-sample threshold -> 32x32 MFMA sweep -> parallel exact refine ====
__global__ __launch_bounds__(NT, 8) void knn_mfma(
    const float* __restrict__ qc, const float* __restrict__ sf,
    const unsigned short* __restrict__ tbl, const float4* __restrict__ tblf,
    float* __restrict__ out)
{
    __shared__ unsigned short s_qvec[QPB][16];   // query K-vectors (1 KB)
    __shared__ float4 s_q[QPB];                  // qx,qy,qz,q2 (f32, refine)
    __shared__ float  s_samp[QPB][8][KNN];       // per-wave sample-top-8 (8 KB)
    __shared__ float  s_thrq[QPB];               // pooled threshold (+MARGIN)
    __shared__ int    s_cnt[QPB];
    __shared__ int    s_cand[QPB][CAP];          // 24 KB
    __shared__ int    s_idx[QPB][KNN];
    __shared__ float  s_w[QPB][KNN];

    const int tid = threadIdx.x;

    // XCD swizzle: batch b -> XCD pair {2b,2b+1}; bijective over 1024 blocks.
    const int p   = blockIdx.x;
    const int b   = (p >> 1) & 3;
    const int sub = ((p >> 3) << 1) | (p & 1);   // 0..255
    const int q0  = b * NQ + sub * QPB;

    // ---- stage query K-vectors + f32 coords ----
    if (tid < QPB) {
        const float* qp = qc + (size_t)(q0 + tid) * 3;
        const float qx = qp[0], qy = qp[1], qz = qp[2];
        const float q2 = __fmaf_rn(qx, qx, __fmaf_rn(qy, qy, __fmul_rn(qz, qz)));
        s_q[tid] = make_float4(qx, qy, qz, q2);
        #pragma unroll
        for (int j = 11; j < 16; ++j) s_qvec[tid][j] = 0;
        const unsigned short one = f2bf(1.0f);
        unsigned short h, l;
        s_qvec[tid][0] = one; s_qvec[tid][1] = one;
        h = f2bf(qx); l = f2bf(qx - bf2f(h));
        s_qvec[tid][2] = h; s_qvec[tid][3] = h; s_qvec[tid][4]  = l;
        h = f2bf(qy); l = f2bf(qy - bf2f(h));
        s_qvec[tid][5] = h; s_qvec[tid][6] = h; s_qvec[tid][7]  = l;
        h = f2bf(qz); l = f2bf(qz - bf2f(h));
        s_qvec[tid][8] = h; s_qvec[tid][9] = h; s_qvec[tid][10] = l;
        s_cnt[tid] = 0;
    }
    __syncthreads();

    const int wid  = tid >> 6;        // wave 0..7 -> tiles [wid*16, wid*16+16)
    const int lane = tid & 63;
    const int ln31 = lane & 31;       // A row within tile / B query col
    const int kc   = lane >> 5;       // k-chunk 0..1 (A/B k = 8*kc + j)
    const int t0   = wid * TPW;

    // B fragment: col = lane&31 (query), k = 8*(lane>>5)+j
    // [analog of the r8 HW-verified 16x16 mapping; C/D layout HW-verified]
    const bf16x8 bfrag = *reinterpret_cast<const bf16x8*>(&s_qvec[ln31][kc * 8]);
    const f32x16 zero = {};

    // A fragment source: row = lane&31 (sensor in tile), k = 8*(lane>>5)+j
    const unsigned short* abase = tbl + ((size_t)ln31 * 16 + kc * 8);

    // ---- pass S: top-8 over 2 sampled tiles (64 sensors/query/wave; 512 pooled) ----
    float kd[KNN];
    #pragma unroll
    for (int j = 0; j < KNN; ++j) kd[j] = 3.4e38f;

    #pragma unroll
    for (int ts = 0; ts < 2; ++ts) {
        const int t = t0 + ts * 8;
        const bf16x8 a = *reinterpret_cast<const bf16x8*>(abase + (size_t)t * 512);
        const f32x16 d = __builtin_amdgcn_mfma_f32_32x32x16_bf16(a, bfrag, zero, 0, 0, 0);
        #pragma unroll
        for (int r = 0; r < 16; ++r) {
            const float x = d[r];
            if (x < kd[KNN-1]) {     // insert is a no-op unless x beats the 8th
                const float nk0 = fminf(kd[0], x);
                #pragma unroll
                for (int j = KNN - 1; j >= 1; --j) kd[j] = med3(kd[j-1], kd[j], x);
                kd[0] = nk0;
            }
        }
    }

    // ---- tournament over the 2 lanes holding this query (xor 32): record top-8 ----
    float smp[KNN];
    #pragma unroll
    for (int r = 0; r < KNN; ++r) {
        float m = fminf(kd[0], __shfl_xor(kd[0], 32, 64));
        const bool pop = (kd[0] == m);   // tie over-pop only RAISES values (safe)
        #pragma unroll
        for (int j = 0; j < KNN - 1; ++j) kd[j] = pop ? kd[j+1] : kd[j];
        kd[KNN-1] = pop ? 3.4e38f : kd[KNN-1];
        smp[r] = m;
    }
    if (lane < 32) {
        #pragma unroll
        for (int r = 0; r < KNN; ++r) s_samp[ln31][wid][r] = smp[r];
    }
    __syncthreads();

    // ---- pool 8x8 wave lists -> pooled sample-8th (rank ~64 of 4096) ----
    if (tid < QPB) {
        float pk[KNN];
        #pragma unroll
        for (int j = 0; j < KNN; ++j) pk[j] = 3.4e38f;
        #pragma unroll
        for (int w8 = 0; w8 < 8; ++w8) {
            #pragma unroll
            for (int r = 0; r < KNN; ++r) {
                const float x = s_samp[tid][w8][r];
                if (x < pk[KNN-1]) {
                    const float nk0 = fminf(pk[0], x);
                    #pragma unroll
                    for (int j = KNN - 1; j >= 1; --j) pk[j] = med3(pk[j-1], pk[j], x);
                    pk[0] = nk0;
                }
            }
        }
        s_thrq[tid] = pk[KNN - 1] + MARGIN;   // superset threshold (proof as r8)
    }
    __syncthreads();

    const float thr_eff = s_thrq[ln31];

    // ---- pass C: sweep this wave's 16 tiles; collect candidate ids ----
    #pragma unroll 2
    for (int t = t0; t < t0 + TPW; ++t) {
        const bf16x8 a = *reinterpret_cast<const bf16x8*>(abase + (size_t)t * 512);
        const f32x16 d = __builtin_amdgcn_mfma_f32_32x32x16_bf16(a, bfrag, zero, 0, 0, 0);
        #pragma unroll
        for (int r = 0; r < 16; ++r) {
            if (d[r] <= thr_eff) {
                // C row = (r&3) + 8*(r>>2) + 4*(lane>>5)  [HW-verified layout]
                const int row = (r & 3) + 8 * (r >> 2) + 4 * kc;
                const int sid = t * 32 + row;
                const int pos = atomicAdd(&s_cnt[ln31], 1);
                if (pos < CAP) s_cand[ln31][pos] = sid;
            }
        }
    }
    __syncthreads();

    // ---- parallel exact refine: wave wid -> queries wid*4..+3 ----
    // 16 lanes per query split candidates; per-lane sorted u64 top-8;
    // 16-lane u64 pop-tournament -> exact top-8 (keys unique -> one pop).
    {
        const int sg = lane >> 4;            // subgroup 0..3
        const int li = lane & 15;            // lane within subgroup
        const int qr = wid * 4 + sg;         // query refined by this subgroup (0..31)
        const int cnt0 = s_cnt[qr];
        const float qx = s_q[qr].x, qy = s_q[qr].y, qz = s_q[qr].z, q2 = s_q[qr].w;

        u64 kb[KNN];
        #pragma unroll
        for (int j = 0; j < KNN; ++j) kb[j] = ~0ull;

        if (cnt0 <= CAP) {
            for (int i = li; i < cnt0; i += 16) {
                const int sid = s_cand[qr][i];
                const float4 m = tblf[sid];
                const float x  = __fmaf_rn(qx, m.x,
                                 __fmaf_rn(qy, m.y, __fmaf_rn(qz, m.z, m.w)));
                const float d2 = fmaxf(__fadd_rn(x, q2), 0.0f);
                u64 cur = ((u64)__float_as_uint(d2) << 32) | (unsigned)sid;
                #pragma unroll
                for (int j = 0; j < KNN; ++j) {
                    const u64 lo = kb[j] < cur ? kb[j] : cur;
                    const u64 hi = kb[j] < cur ? cur : kb[j];
                    kb[j] = lo; cur = hi;
                }
            }
        } else {
            // safety net (>=5.5 sigma): exact full scan, split over 16 lanes
            for (int sid = li; sid < NS; sid += 16) {
                const float4 m = tblf[sid];
                const float x  = __fmaf_rn(qx, m.x,
                                 __fmaf_rn(qy, m.y, __fmaf_rn(qz, m.z, m.w)));
                const float d2 = fmaxf(__fadd_rn(x, q2), 0.0f);
                u64 cur = ((u64)__float_as_uint(d2) << 32) | (unsigned)sid;
                #pragma unroll
                for (int j = 0; j < KNN; ++j) {
                    const u64 lo = kb[j] < cur ? kb[j] : cur;
                    const u64 hi = kb[j] < cur ? cur : kb[j];
                    kb[j] = lo; cur = hi;
                }
            }
        }

        u64 sel = ~0ull;
        #pragma unroll
        for (int r = 0; r < KNN; ++r) {
            u64 v = kb[0];
            #pragma unroll
            for (int m = 1; m <= 8; m <<= 1) {
                const u64 o = __shfl_xor(v, m, 64);   // stays within 16-lane group
                v = o < v ? o : v;
            }
            const bool pop = (kb[0] == v);
            #pragma unroll
            for (int j = 0; j < KNN - 1; ++j) kb[j] = pop ? kb[j+1] : kb[j];
            kb[KNN-1] = pop ? ~0ull : kb[KNN-1];
            if (li == r) sel = v;
        }

        // weights on lanes 0..7 of each subgroup (xor 1,2,4 stays within 0..7)
        const float d2v = __uint_as_float((unsigned)(sel >> 32));
        const int   idx = (int)(unsigned)(sel & 0xFFFFFFFFu);
        const float w   = 1.0f / (sqrtf(d2v) + 1e-8f);
        float ws = w;
        ws += __shfl_xor(ws, 1, 64);
        ws += __shfl_xor(ws, 2, 64);
        ws += __shfl_xor(ws, 4, 64);
        if (li < KNN) {
            s_idx[qr][li] = idx;
            s_w[qr][li]   = w / ws;
        }
    }
    __syncthreads();

    // ---- gather: wave wid -> queries wid*4..+3; 64 lanes x float4 ----
    const float* fb = sf + (size_t)b * NS * FDIM;
    #pragma unroll 1
    for (int jq = 0; jq < QPB / 8; ++jq) {
        const int ql = wid * (QPB / 8) + jq;
        float4 acc = {0.f, 0.f, 0.f, 0.f};
        #pragma unroll
        for (int kk = 0; kk < KNN; ++kk) {
            const int   sid = s_idx[ql][kk];
            const float wk  = s_w[ql][kk];
            const float4 v = ((const float4*)(fb + (size_t)sid * FDIM))[lane];
            acc.x += wk * v.x; acc.y += wk * v.y;
            acc.z += wk * v.z; acc.w += wk * v.w;
        }
        ((float4*)(out + (size_t)(q0 + ql) * FDIM))[lane] = acc;
    }
}

// ================= fallback (round-6 kernel) if workspace too small =================
#define FG    16
#define FQL   2
#define FNT   512
#define FGRP  (FNT / FG)
#define FQPB  (FGRP * FQL)
#define FSCAN (NS / FG)
#define FCAP  16

#define FKEYX(m, qq) __fmaf_rn(fqx[qq], (m).x, \
                     __fmaf_rn(fqy[qq], (m).y, \
                     __fmaf_rn(fqz[qq], (m).z, (m).w)))

__global__ __launch_bounds__(FNT, 4) void idw_fallback(
    const float* __restrict__ qc, const float* __restrict__ sc,
    const float* __restrict__ sf, float* __restrict__ out)
{
    __shared__ float4 s_m[NS];
    __shared__ u64    s_items[FQPB * FCAP];
    __shared__ int    s_cnt[FQPB];
    __shared__ int    s_idx[FQPB * KNN];
    __shared__ float  s_w[FQPB * KNN];

    const int tid = threadIdx.x;
    const int p   = blockIdx.x;
    const int b   = (p >> 1) & 3;
    const int sub = ((p >> 3) << 1) | (p & 1);
    const int q0  = b * NQ + sub * FQPB;

    for (int s = tid; s < NS; s += FNT) {
        const float sx = sc[3*s+0], sy = sc[3*s+1], sz = sc[3*s+2];
        const float s2 = __fmaf_rn(sx, sx, __fmaf_rn(sy, sy, __fmul_rn(sz, sz)));
        s_m[s] = make_float4(-2.0f*sx, -2.0f*sy, -2.0f*sz, s2);
    }
    if (tid < FQPB) s_cnt[tid] = 0;
    __syncthreads();

    const int g = tid >> 4, l = tid & 15;
    float fqx[FQL], fqy[FQL], fqz[FQL], fq2[FQL];
    #pragma unroll
    for (int qq = 0; qq < FQL; ++qq) {
        const float* qp = qc + (size_t)(q0 + g * FQL + qq) * 3;
        fqx[qq] = qp[0]; fqy[qq] = qp[1]; fqz[qq] = qp[2];
        fq2[qq] = __fmaf_rn(fqx[qq], fqx[qq],
                  __fmaf_rn(fqy[qq], fqy[qq], __fmul_rn(fqz[qq], fqz[qq])));
    }

    float kd[FQL][KNN];
    #pragma unroll
    for (int qq = 0; qq < FQL; ++qq)
        #pragma unroll
        for (int j = 0; j < KNN; ++j) kd[qq][j] = 3.4e38f;

    #pragma unroll 2
    for (int t = 0; t < FSCAN; ++t) {
        const float4 m = s_m[t * FG + l];
        #pragma unroll
        for (int qq = 0; qq < FQL; ++qq) {
            const float x = FKEYX(m, qq);
            const float nk0 = fminf(kd[qq][0], x);
            #pragma unroll
            for (int j = KNN - 1; j >= 1; --j)
                kd[qq][j] = med3(kd[qq][j-1], kd[qq][j], x);
            kd[qq][0] = nk0;
        }
    }

    float thr[FQL];
    #pragma unroll
    for (int qq = 0; qq < FQL; ++qq) {
        float thv = 3.4e38f;
        #pragma unroll
        for (int r = 0; r < KNN; ++r) {
            float m = kd[qq][0];
            m = fminf(m, __shfl_xor(m, 1, 64));
            m = fminf(m, __shfl_xor(m, 2, 64));
            m = fminf(m, __shfl_xor(m, 4, 64));
            m = fminf(m, __shfl_xor(m, 8, 64));
            const bool pop = (kd[qq][0] == m);
            #pragma unroll
            for (int j = 0; j < KNN - 1; ++j) kd[qq][j] = pop ? kd[qq][j+1] : kd[qq][j];
            kd[qq][KNN-1] = pop ? 3.4e38f : kd[qq][KNN-1];
            thv = m;
        }
        thr[qq] = thv;
    }

    #pragma unroll 2
    for (int t = 0; t < FSCAN; ++t) {
        const int s = t * FG + l;
        const float4 m = s_m[s];
        #pragma unroll
        for (int qq = 0; qq < FQL; ++qq) {
            const float x = FKEYX(m, qq);
            if (x <= thr[qq]) {
                const float dc = fmaxf(__fadd_rn(x, fq2[qq]), 0.0f);
                const u64 key = ((u64)__float_as_uint(dc) << 32) | (unsigned)s;
                const int qid = g * FQL + qq;
                const int pos = atomicAdd(&s_cnt[qid], 1);
                if (pos < FCAP) s_items[qid * FCAP + pos] = key;
            }
        }
    }
    __syncthreads();

    if (l < FQL) {
        const int qid = g * FQL + l;
        int cnt = s_cnt[qid];
        if (cnt > KNN) {
            cnt = cnt < FCAP ? cnt : FCAP;
            u64 best[KNN];
            #pragma unroll
            for (int j = 0; j < KNN; ++j) best[j] = ~0ull;
            for (int i = 0; i < cnt; ++i) {
                u64 cur = s_items[qid * FCAP + i];
                #pragma unroll
                for (int j = 0; j < KNN; ++j) {
                    const u64 lo = best[j] < cur ? best[j] : cur;
                    const u64 hi = best[j] < cur ? cur : best[j];
                    best[j] = lo; cur = hi;
                }
            }
            #pragma unroll
            for (int j = 0; j < KNN; ++j) s_items[qid * FCAP + j] = best[j];
        }
    }
    __syncthreads();

    {
        const int qq  = l >> 3;
        const int k   = l & 7;
        const int qid = g * FQL + qq;
        const u64 key = s_items[qid * FCAP + k];
        const float d2v = __uint_as_float((unsigned)(key >> 32));
        const int   idx = (int)(unsigned)(key & 0xFFFFFFFFu);
        const float w   = 1.0f / (sqrtf(d2v) + 1e-8f);
        float ws = w;
        ws += __shfl_xor(ws, 1, 64);
        ws += __shfl_xor(ws, 2, 64);
        ws += __shfl_xor(ws, 4, 64);
        s_idx[qid * KNN + k] = idx;
        s_w  [qid * KNN + k] = w / ws;
    }
    __syncthreads();

    const int wave = tid >> 6, lane = tid & 63;
    const float* fb = sf + (size_t)b * NS * FDIM;
    #pragma unroll 1
    for (int j = 0; j < FQPB / 8; ++j) {
        const int ql = wave * (FQPB / 8) + j;
        float4 acc = {0.f, 0.f, 0.f, 0.f};
        #pragma unroll
        for (int kk = 0; kk < KNN; ++kk) {
            const int   sid = s_idx[ql * KNN + kk];
            const float wk  = s_w  [ql * KNN + kk];
            const float4 v = ((const float4*)(fb + (size_t)sid * FDIM))[lane];
            acc.x += wk * v.x; acc.y += wk * v.y;
            acc.z += wk * v.z; acc.w += wk * v.w;
        }
        ((float4*)(out + (size_t)(q0 + ql) * FDIM))[lane] = acc;
    }
}

extern "C" void kernel_launch(void* const* d_in, const int* in_sizes, int n_in,
                              void* d_out, int out_size, void* d_ws, size_t ws_size,
                              hipStream_t stream) {
    const float* qc = (const float*)d_in[0];   // query_coords  (4,8192,3)
    const float* sc = (const float*)d_in[1];   // sensor_coords (4096,3)
    const float* sf = (const float*)d_in[2];   // sensor_features (4,4096,256)
    float* out = (float*)d_out;                // (4,8192,256)

    if (ws_size >= (size_t)WS_NEED) {
        unsigned short* tbl  = (unsigned short*)d_ws;
        float4*         tblf = (float4*)((char*)d_ws + WS_TBLF);
        build_tbl<<<NS / 256, 256, 0, stream>>>(sc, tbl, tblf);
        knn_mfma<<<(BB * NQ) / QPB, NT, 0, stream>>>(qc, sf, tbl, tblf, out);
    } else {
        idw_fallback<<<(BB * NQ) / FQPB, FNT, 0, stream>>>(qc, sc, sf, out);
    }
}

// Round 14
// 66.332 us; speedup vs baseline: 1.1493x; 1.0501x over previous
//
#include <hip/hip_runtime.h>
#include <hip/hip_bf16.h>
#include <stdint.h>

#define BB    4
#define NQ    8192
#define NS    4096
#define FDIM  256
#define KNN   8
#define NT    512                // 8 waves; wave w owns tiles [16w,16w+16)
#define QPB   32                 // queries per block (one 32-col MFMA B set)
#define CAP   196                // candidate capacity (E=64; 196%32!=0 de-aliases banks)
#define MARGIN 0.0035f           // > 2x bf16-split error bound (~1.1e-3)
#define NTILES 128               // NS/32 total 32-sensor tiles
#define TPW   16                 // tiles per wave

typedef unsigned long long u64;
typedef __attribute__((ext_vector_type(8)))  short bf16x8;   // 8 bf16 (4 VGPR)
typedef __attribute__((ext_vector_type(16))) float f32x16;   // 32x32 C/D

__device__ __forceinline__ float med3(float a, float b, float c) {
    return __builtin_amdgcn_fmed3f(a, b, c);
}
__device__ __forceinline__ unsigned short f2bf(float v) {
    __hip_bfloat16 h = __float2bfloat16(v);
    return *reinterpret_cast<unsigned short*>(&h);
}
__device__ __forceinline__ float bf2f(unsigned short u) {
    __hip_bfloat16 h;
    *reinterpret_cast<unsigned short*>(&h) = u;
    return __bfloat162float(h);
}

// ---------------- d_ws layout ----------------
// tbl  : [NS][16] bf16 @ 0       (128 KB)  K=16 vectors (11 slots used)
// tblf : [NS] float4  @ 131072   (64 KB)   (-2x,-2y,-2z,s^2) f32 for refine
#define WS_TBLF  131072
#define WS_NEED  196608

// ============ build: bf16 K-vector table + f32 refine table ============
// k: 0:s2_hi 1:s2_lo 2:mx_hi 3:mx_lo 4:mx_hi 5:my_hi 6:my_lo 7:my_hi
//    8:mz_hi 9:mz_lo 10:mz_hi 11..15:0        (m* = -2*coord)
__global__ __launch_bounds__(256) void build_tbl(const float* __restrict__ sc,
                                                 unsigned short* __restrict__ tbl,
                                                 float4* __restrict__ tblf) {
    const int s = blockIdx.x * 256 + threadIdx.x;
    if (s >= NS) return;
    const float sx = sc[3*s], sy = sc[3*s+1], sz = sc[3*s+2];
    const float s2 = __fmaf_rn(sx, sx, __fmaf_rn(sy, sy, __fmul_rn(sz, sz)));
    const float mx = -2.0f*sx, my = -2.0f*sy, mz = -2.0f*sz;
    unsigned short e[16];
    #pragma unroll
    for (int j = 0; j < 16; ++j) e[j] = 0;
    unsigned short h, l;
    h = f2bf(s2); l = f2bf(s2 - bf2f(h)); e[0] = h; e[1] = l;
    h = f2bf(mx); l = f2bf(mx - bf2f(h)); e[2] = h; e[3] = l; e[4]  = h;
    h = f2bf(my); l = f2bf(my - bf2f(h)); e[5] = h; e[6] = l; e[7]  = h;
    h = f2bf(mz); l = f2bf(mz - bf2f(h)); e[8] = h; e[9] = l; e[10] = h;
    #pragma unroll
    for (int j = 0; j < 16; ++j) tbl[s * 16 + j] = e[j];
    tblf[s] = make_float4(mx, my, mz, s2);
}

// ===== main: pooled-sample threshold -> 32x32 MFMA sweep -> parallel exact refine ====
__global__ __launch_bounds__(NT, 8) void knn_mfma(
    const float* __restrict__ qc, const float* __restrict__ sf,
    const unsigned short* __restrict__ tbl, const float4* __restrict__ tblf,
    float* __restrict__ out)
{
    __shared__ unsigned short s_qvec[QPB][16];   // query K-vectors (1 KB)
    __shared__ float4 s_q[QPB];                  // qx,qy,qz,q2 (f32, refine)
    __shared__ float  s_samp[8][KNN][QPB];       // TRANSPOSED: lane-stride-1 writes
    __shared__ float  s_thrq[QPB];               // pooled threshold (+MARGIN)
    __shared__ int    s_cnt[QPB];
    __shared__ int    s_cand[QPB][CAP];          // ~25 KB
    __shared__ int    s_idx[QPB][KNN];
    __shared__ float  s_w[QPB][KNN];

    const int tid = threadIdx.x;

    // XCD swizzle: batch b -> XCD pair {2b,2b+1}; bijective over 1024 blocks.
    const int p   = blockIdx.x;
    const int b   = (p >> 1) & 3;
    const int sub = ((p >> 3) << 1) | (p & 1);   // 0..255
    const int q0  = b * NQ + sub * QPB;

    // ---- stage query K-vectors + f32 coords ----
    if (tid < QPB) {
        const float* qp = qc + (size_t)(q0 + tid) * 3;
        const float qx = qp[0], qy = qp[1], qz = qp[2];
        const float q2 = __fmaf_rn(qx, qx, __fmaf_rn(qy, qy, __fmul_rn(qz, qz)));
        s_q[tid] = make_float4(qx, qy, qz, q2);
        #pragma unroll
        for (int j = 11; j < 16; ++j) s_qvec[tid][j] = 0;
        const unsigned short one = f2bf(1.0f);
        unsigned short h, l;
        s_qvec[tid][0] = one; s_qvec[tid][1] = one;
        h = f2bf(qx); l = f2bf(qx - bf2f(h));
        s_qvec[tid][2] = h; s_qvec[tid][3] = h; s_qvec[tid][4]  = l;
        h = f2bf(qy); l = f2bf(qy - bf2f(h));
        s_qvec[tid][5] = h; s_qvec[tid][6] = h; s_qvec[tid][7]  = l;
        h = f2bf(qz); l = f2bf(qz - bf2f(h));
        s_qvec[tid][8] = h; s_qvec[tid][9] = h; s_qvec[tid][10] = l;
        s_cnt[tid] = 0;
    }
    __syncthreads();

    const int wid  = tid >> 6;        // wave 0..7 -> tiles [wid*16, wid*16+16)
    const int lane = tid & 63;
    const int ln31 = lane & 31;       // A row within tile / B query col
    const int kc   = lane >> 5;       // k-chunk 0..1 (A/B k = 8*kc + j)
    const int t0   = wid * TPW;

    // B fragment: col = lane&31 (query), k = 8*(lane>>5)+j  [r13-verified]
    const bf16x8 bfrag = *reinterpret_cast<const bf16x8*>(&s_qvec[ln31][kc * 8]);
    const f32x16 zero = {};

    // A fragment source: row = lane&31 (sensor in tile), k = 8*(lane>>5)+j
    const unsigned short* abase = tbl + ((size_t)ln31 * 16 + kc * 8);

    // ---- pass S: top-8 over 2 sampled tiles (64 sensors/query/wave; 512 pooled) ----
    float kd[KNN];
    #pragma unroll
    for (int j = 0; j < KNN; ++j) kd[j] = 3.4e38f;

    #pragma unroll
    for (int ts = 0; ts < 2; ++ts) {
        const int t = t0 + ts * 8;
        const bf16x8 a = *reinterpret_cast<const bf16x8*>(abase + (size_t)t * 512);
        const f32x16 d = __builtin_amdgcn_mfma_f32_32x32x16_bf16(a, bfrag, zero, 0, 0, 0);
        #pragma unroll
        for (int r = 0; r < 16; ++r) {
            const float x = d[r];
            if (x < kd[KNN-1]) {     // insert is a no-op unless x beats the 8th
                const float nk0 = fminf(kd[0], x);
                #pragma unroll
                for (int j = KNN - 1; j >= 1; --j) kd[j] = med3(kd[j-1], kd[j], x);
                kd[0] = nk0;
            }
        }
    }

    // ---- tournament over the 2 lanes holding this query (xor 32): record top-8 ----
    float smp[KNN];
    #pragma unroll
    for (int r = 0; r < KNN; ++r) {
        float m = fminf(kd[0], __shfl_xor(kd[0], 32, 64));
        const bool pop = (kd[0] == m);   // tie over-pop only RAISES values (safe)
        #pragma unroll
        for (int j = 0; j < KNN - 1; ++j) kd[j] = pop ? kd[j+1] : kd[j];
        kd[KNN-1] = pop ? 3.4e38f : kd[KNN-1];
        smp[r] = m;
    }
    if (lane < 32) {
        #pragma unroll
        for (int r = 0; r < KNN; ++r) s_samp[wid][r][ln31] = smp[r];  // stride-1
    }
    __syncthreads();

    // ---- parallel pool: subgroup (wid,sg) pools query qr = wid*4+sg ----
    // 64 sample values; lane li holds 4 sorted; 8-round 16-lane pop-tournament
    // -> pooled sample-8th (tie over-pop only raises thr; refine is exact anyway).
    {
        const int sg = lane >> 4;
        const int li = lane & 15;
        const int qr = wid * 4 + sg;
        const int v0 = li * 4;
        const float x0 = s_samp[(v0+0) >> 3][(v0+0) & 7][qr];
        const float x1 = s_samp[(v0+1) >> 3][(v0+1) & 7][qr];
        const float x2 = s_samp[(v0+2) >> 3][(v0+2) & 7][qr];
        const float x3 = s_samp[(v0+3) >> 3][(v0+3) & 7][qr];
        // sort-4 network (ascending)
        const float a0 = fminf(x0, x1), a1 = fmaxf(x0, x1);
        const float a2 = fminf(x2, x3), a3 = fmaxf(x2, x3);
        const float b0 = fminf(a0, a2), b2 = fmaxf(a0, a2);
        const float b1 = fminf(a1, a3), b3 = fmaxf(a1, a3);
        float l0 = b0, l1 = fminf(b1, b2), l2 = fmaxf(b1, b2), l3 = b3;
        float m = 3.4e38f;
        #pragma unroll
        for (int r = 0; r < KNN; ++r) {
            m = l0;
            m = fminf(m, __shfl_xor(m, 1, 64));
            m = fminf(m, __shfl_xor(m, 2, 64));
            m = fminf(m, __shfl_xor(m, 4, 64));
            m = fminf(m, __shfl_xor(m, 8, 64));
            const bool pop = (l0 == m);
            l0 = pop ? l1 : l0;
            l1 = pop ? l2 : l1;
            l2 = pop ? l3 : l2;
            l3 = pop ? 3.4e38f : l3;
        }
        if (li == 0) s_thrq[qr] = m + MARGIN;   // superset threshold (proof as r8)
    }
    __syncthreads();

    const float thr_eff = s_thrq[ln31];

    // ---- pass C: sweep this wave's 16 tiles (A-load software-pipelined) ----
    {
        bf16x8 a = *reinterpret_cast<const bf16x8*>(abase + (size_t)t0 * 512);
        #pragma unroll 2
        for (int tt = 0; tt < TPW; ++tt) {
            const int t = t0 + tt;
            bf16x8 an = a;
            if (tt + 1 < TPW)
                an = *reinterpret_cast<const bf16x8*>(abase + (size_t)(t + 1) * 512);
            const f32x16 d = __builtin_amdgcn_mfma_f32_32x32x16_bf16(a, bfrag, zero, 0, 0, 0);
            #pragma unroll
            for (int r = 0; r < 16; ++r) {
                if (d[r] <= thr_eff) {
                    // C row = (r&3) + 8*(r>>2) + 4*(lane>>5)  [r13-verified layout]
                    const int row = (r & 3) + 8 * (r >> 2) + 4 * kc;
                    const int sid = t * 32 + row;
                    const int pos = atomicAdd(&s_cnt[ln31], 1);
                    if (pos < CAP) s_cand[ln31][pos] = sid;
                }
            }
            a = an;
        }
    }
    __syncthreads();

    // ---- parallel exact refine: wave wid -> queries wid*4..+3 ----
    // 16 lanes per query split candidates; per-lane sorted u64 top-8;
    // 16-lane u64 pop-tournament -> exact top-8 (keys unique -> one pop).
    {
        const int sg = lane >> 4;            // subgroup 0..3
        const int li = lane & 15;            // lane within subgroup
        const int qr = wid * 4 + sg;         // query refined by this subgroup (0..31)
        const int cnt0 = s_cnt[qr];
        const float qx = s_q[qr].x, qy = s_q[qr].y, qz = s_q[qr].z, q2 = s_q[qr].w;

        u64 kb[KNN];
        #pragma unroll
        for (int j = 0; j < KNN; ++j) kb[j] = ~0ull;

        if (cnt0 <= CAP) {
            for (int i = li; i < cnt0; i += 16) {
                const int sid = s_cand[qr][i];
                const float4 m = tblf[sid];
                const float x  = __fmaf_rn(qx, m.x,
                                 __fmaf_rn(qy, m.y, __fmaf_rn(qz, m.z, m.w)));
                const float d2 = fmaxf(__fadd_rn(x, q2), 0.0f);
                u64 cur = ((u64)__float_as_uint(d2) << 32) | (unsigned)sid;
                #pragma unroll
                for (int j = 0; j < KNN; ++j) {
                    const u64 lo = kb[j] < cur ? kb[j] : cur;
                    const u64 hi = kb[j] < cur ? cur : kb[j];
                    kb[j] = lo; cur = hi;
                }
            }
        } else {
            // safety net (>=5.5 sigma): exact full scan, split over 16 lanes
            for (int sid = li; sid < NS; sid += 16) {
                const float4 m = tblf[sid];
                const float x  = __fmaf_rn(qx, m.x,
                                 __fmaf_rn(qy, m.y, __fmaf_rn(qz, m.z, m.w)));
                const float d2 = fmaxf(__fadd_rn(x, q2), 0.0f);
                u64 cur = ((u64)__float_as_uint(d2) << 32) | (unsigned)sid;
                #pragma unroll
                for (int j = 0; j < KNN; ++j) {
                    const u64 lo = kb[j] < cur ? kb[j] : cur;
                    const u64 hi = kb[j] < cur ? cur : kb[j];
                    kb[j] = lo; cur = hi;
                }
            }
        }

        u64 sel = ~0ull;
        #pragma unroll
        for (int r = 0; r < KNN; ++r) {
            u64 v = kb[0];
            #pragma unroll
            for (int m = 1; m <= 8; m <<= 1) {
                const u64 o = __shfl_xor(v, m, 64);   // stays within 16-lane group
                v = o < v ? o : v;
            }
            const bool pop = (kb[0] == v);
            #pragma unroll
            for (int j = 0; j < KNN - 1; ++j) kb[j] = pop ? kb[j+1] : kb[j];
            kb[KNN-1] = pop ? ~0ull : kb[KNN-1];
            if (li == r) sel = v;
        }

        // weights on lanes 0..7 of each subgroup (xor 1,2,4 stays within 0..7)
        const float d2v = __uint_as_float((unsigned)(sel >> 32));
        const int   idx = (int)(unsigned)(sel & 0xFFFFFFFFu);
        const float w   = 1.0f / (sqrtf(d2v) + 1e-8f);
        float ws = w;
        ws += __shfl_xor(ws, 1, 64);
        ws += __shfl_xor(ws, 2, 64);
        ws += __shfl_xor(ws, 4, 64);
        if (li < KNN) {
            s_idx[qr][li] = idx;
            s_w[qr][li]   = w / ws;
        }
    }
    __syncthreads();

    // ---- gather: wave wid -> queries wid*4..+3; 64 lanes x float4 ----
    const float* fb = sf + (size_t)b * NS * FDIM;
    #pragma unroll 1
    for (int jq = 0; jq < QPB / 8; ++jq) {
        const int ql = wid * (QPB / 8) + jq;
        float4 acc = {0.f, 0.f, 0.f, 0.f};
        #pragma unroll
        for (int kk = 0; kk < KNN; ++kk) {
            const int   sid = s_idx[ql][kk];
            const float wk  = s_w[ql][kk];
            const float4 v = ((const float4*)(fb + (size_t)sid * FDIM))[lane];
            acc.x += wk * v.x; acc.y += wk * v.y;
            acc.z += wk * v.z; acc.w += wk * v.w;
        }
        ((float4*)(out + (size_t)(q0 + ql) * FDIM))[lane] = acc;
    }
}

// ================= fallback (round-6 kernel) if workspace too small =================
#define FG    16
#define FQL   2
#define FNT   512
#define FGRP  (FNT / FG)
#define FQPB  (FGRP * FQL)
#define FSCAN (NS / FG)
#define FCAP  16

#define FKEYX(m, qq) __fmaf_rn(fqx[qq], (m).x, \
                     __fmaf_rn(fqy[qq], (m).y, \
                     __fmaf_rn(fqz[qq], (m).z, (m).w)))

__global__ __launch_bounds__(FNT, 4) void idw_fallback(
    const float* __restrict__ qc, const float* __restrict__ sc,
    const float* __restrict__ sf, float* __restrict__ out)
{
    __shared__ float4 s_m[NS];
    __shared__ u64    s_items[FQPB * FCAP];
    __shared__ int    s_cnt[FQPB];
    __shared__ int    s_idx[FQPB * KNN];
    __shared__ float  s_w[FQPB * KNN];

    const int tid = threadIdx.x;
    const int p   = blockIdx.x;
    const int b   = (p >> 1) & 3;
    const int sub = ((p >> 3) << 1) | (p & 1);
    const int q0  = b * NQ + sub * FQPB;

    for (int s = tid; s < NS; s += FNT) {
        const float sx = sc[3*s+0], sy = sc[3*s+1], sz = sc[3*s+2];
        const float s2 = __fmaf_rn(sx, sx, __fmaf_rn(sy, sy, __fmul_rn(sz, sz)));
        s_m[s] = make_float4(-2.0f*sx, -2.0f*sy, -2.0f*sz, s2);
    }
    if (tid < FQPB) s_cnt[tid] = 0;
    __syncthreads();

    const int g = tid >> 4, l = tid & 15;
    float fqx[FQL], fqy[FQL], fqz[FQL], fq2[FQL];
    #pragma unroll
    for (int qq = 0; qq < FQL; ++qq) {
        const float* qp = qc + (size_t)(q0 + g * FQL + qq) * 3;
        fqx[qq] = qp[0]; fqy[qq] = qp[1]; fqz[qq] = qp[2];
        fq2[qq] = __fmaf_rn(fqx[qq], fqx[qq],
                  __fmaf_rn(fqy[qq], fqy[qq], __fmul_rn(fqz[qq], fqz[qq])));
    }

    float kd[FQL][KNN];
    #pragma unroll
    for (int qq = 0; qq < FQL; ++qq)
        #pragma unroll
        for (int j = 0; j < KNN; ++j) kd[qq][j] = 3.4e38f;

    #pragma unroll 2
    for (int t = 0; t < FSCAN; ++t) {
        const float4 m = s_m[t * FG + l];
        #pragma unroll
        for (int qq = 0; qq < FQL; ++qq) {
            const float x = FKEYX(m, qq);
            const float nk0 = fminf(kd[qq][0], x);
            #pragma unroll
            for (int j = KNN - 1; j >= 1; --j)
                kd[qq][j] = med3(kd[qq][j-1], kd[qq][j], x);
            kd[qq][0] = nk0;
        }
    }

    float thr[FQL];
    #pragma unroll
    for (int qq = 0; qq < FQL; ++qq) {
        float thv = 3.4e38f;
        #pragma unroll
        for (int r = 0; r < KNN; ++r) {
            float m = kd[qq][0];
            m = fminf(m, __shfl_xor(m, 1, 64));
            m = fminf(m, __shfl_xor(m, 2, 64));
            m = fminf(m, __shfl_xor(m, 4, 64));
            m = fminf(m, __shfl_xor(m, 8, 64));
            const bool pop = (kd[qq][0] == m);
            #pragma unroll
            for (int j = 0; j < KNN - 1; ++j) kd[qq][j] = pop ? kd[qq][j+1] : kd[qq][j];
            kd[qq][KNN-1] = pop ? 3.4e38f : kd[qq][KNN-1];
            thv = m;
        }
        thr[qq] = thv;
    }

    #pragma unroll 2
    for (int t = 0; t < FSCAN; ++t) {
        const int s = t * FG + l;
        const float4 m = s_m[s];
        #pragma unroll
        for (int qq = 0; qq < FQL; ++qq) {
            const float x = FKEYX(m, qq);
            if (x <= thr[qq]) {
                const float dc = fmaxf(__fadd_rn(x, fq2[qq]), 0.0f);
                const u64 key = ((u64)__float_as_uint(dc) << 32) | (unsigned)s;
                const int qid = g * FQL + qq;
                const int pos = atomicAdd(&s_cnt[qid], 1);
                if (pos < FCAP) s_items[qid * FCAP + pos] = key;
            }
        }
    }
    __syncthreads();

    if (l < FQL) {
        const int qid = g * FQL + l;
        int cnt = s_cnt[qid];
        if (cnt > KNN) {
            cnt = cnt < FCAP ? cnt : FCAP;
            u64 best[KNN];
            #pragma unroll
            for (int j = 0; j < KNN; ++j) best[j] = ~0ull;
            for (int i = 0; i < cnt; ++i) {
                u64 cur = s_items[qid * FCAP + i];
                #pragma unroll
                for (int j = 0; j < KNN; ++j) {
                    const u64 lo = best[j] < cur ? best[j] : cur;
                    const u64 hi = best[j] < cur ? cur : best[j];
                    best[j] = lo; cur = hi;
                }
            }
            #pragma unroll
            for (int j = 0; j < KNN; ++j) s_items[qid * FCAP + j] = best[j];
        }
    }
    __syncthreads();

    {
        const int qq  = l >> 3;
        const int k   = l & 7;
        const int qid = g * FQL + qq;
        const u64 key = s_items[qid * FCAP + k];
        const float d2v = __uint_as_float((unsigned)(key >> 32));
        const int   idx = (int)(unsigned)(key & 0xFFFFFFFFu);
        const float w   = 1.0f / (sqrtf(d2v) + 1e-8f);
        float ws = w;
        ws += __shfl_xor(ws, 1, 64);
        ws += __shfl_xor(ws, 2, 64);
        ws += __shfl_xor(ws, 4, 64);
        s_idx[qid * KNN + k] = idx;
        s_w  [qid * KNN + k] = w / ws;
    }
    __syncthreads();

    const int wave = tid >> 6, lane = tid & 63;
    const float* fb = sf + (size_t)b * NS * FDIM;
    #pragma unroll 1
    for (int j = 0; j < FQPB / 8; ++j) {
        const int ql = wave * (FQPB / 8) + j;
        float4 acc = {0.f, 0.f, 0.f, 0.f};
        #pragma unroll
        for (int kk = 0; kk < KNN; ++kk) {
            const int   sid = s_idx[ql * KNN + kk];
            const float wk  = s_w  [ql * KNN + kk];
            const float4 v = ((const float4*)(fb + (size_t)sid * FDIM))[lane];
            acc.x += wk * v.x; acc.y += wk * v.y;
            acc.z += wk * v.z; acc.w += wk * v.w;
        }
        ((float4*)(out + (size_t)(q0 + ql) * FDIM))[lane] = acc;
    }
}

extern "C" void kernel_launch(void* const* d_in, const int* in_sizes, int n_in,
                              void* d_out, int out_size, void* d_ws, size_t ws_size,
                              hipStream_t stream) {
    const float* qc = (const float*)d_in[0];   // query_coords  (4,8192,3)
    const float* sc = (const float*)d_in[1];   // sensor_coords (4096,3)
    const float* sf = (const float*)d_in[2];   // sensor_features (4,4096,256)
    float* out = (float*)d_out;                // (4,8192,256)

    if (ws_size >= (size_t)WS_NEED) {
        unsigned short* tbl  = (unsigned short*)d_ws;
        float4*         tblf = (float4*)((char*)d_ws + WS_TBLF);
        build_tbl<<<NS / 256, 256, 0, stream>>>(sc, tbl, tblf);
        knn_mfma<<<(BB * NQ) / QPB, NT, 0, stream>>>(qc, sf, tbl, tblf, out);
    } else {
        idw_fallback<<<(BB * NQ) / FQPB, FNT, 0, stream>>>(qc, sc, sf, out);
    }
}

// Round 15
// 64.041 us; speedup vs baseline: 1.1904x; 1.0358x over previous
//
#include <hip/hip_runtime.h>
#include <hip/hip_bf16.h>
#include <stdint.h>

#define BB    4
#define NQ    8192
#define NS    4096
#define FDIM  256
#define KNN   8
#define NT    512                // 8 waves; wave w owns tiles [16w,16w+16)
#define QPB   32                 // queries per block (one 32-col MFMA B set)
#define CAP   128                // candidate capacity (E=32, sigma~10 -> ~10 sigma)
#define MARGIN 0.0035f           // > 2x bf16-split error bound (~1.1e-3)
#define NTILES 128               // NS/32 total 32-sensor tiles
#define TPW   16                 // tiles per wave
#define SAMPT 4                  // sampled tiles per wave (1024 pooled samples)

typedef unsigned long long u64;
typedef __attribute__((ext_vector_type(8)))  short bf16x8;   // 8 bf16 (4 VGPR)
typedef __attribute__((ext_vector_type(16))) float f32x16;   // 32x32 C/D

__device__ __forceinline__ float med3(float a, float b, float c) {
    return __builtin_amdgcn_fmed3f(a, b, c);
}
__device__ __forceinline__ unsigned short f2bf(float v) {
    __hip_bfloat16 h = __float2bfloat16(v);
    return *reinterpret_cast<unsigned short*>(&h);
}
__device__ __forceinline__ float bf2f(unsigned short u) {
    __hip_bfloat16 h;
    *reinterpret_cast<unsigned short*>(&h) = u;
    return __bfloat162float(h);
}

// ---------------- d_ws layout ----------------
// tbl  : [NS][16] bf16 @ 0       (128 KB)  K=16 vectors (11 slots used)
// tblf : [NS] float4  @ 131072   (64 KB)   (-2x,-2y,-2z,s^2) f32 for refine
#define WS_TBLF  131072
#define WS_NEED  196608

// ============ build: bf16 K-vector table + f32 refine table ============
// k: 0:s2_hi 1:s2_lo 2:mx_hi 3:mx_lo 4:mx_hi 5:my_hi 6:my_lo 7:my_hi
//    8:mz_hi 9:mz_lo 10:mz_hi 11..15:0        (m* = -2*coord)
__global__ __launch_bounds__(256) void build_tbl(const float* __restrict__ sc,
                                                 unsigned short* __restrict__ tbl,
                                                 float4* __restrict__ tblf) {
    const int s = blockIdx.x * 256 + threadIdx.x;
    if (s >= NS) return;
    const float sx = sc[3*s], sy = sc[3*s+1], sz = sc[3*s+2];
    const float s2 = __fmaf_rn(sx, sx, __fmaf_rn(sy, sy, __fmul_rn(sz, sz)));
    const float mx = -2.0f*sx, my = -2.0f*sy, mz = -2.0f*sz;
    unsigned short e[16];
    #pragma unroll
    for (int j = 0; j < 16; ++j) e[j] = 0;
    unsigned short h, l;
    h = f2bf(s2); l = f2bf(s2 - bf2f(h)); e[0] = h; e[1] = l;
    h = f2bf(mx); l = f2bf(mx - bf2f(h)); e[2] = h; e[3] = l; e[4]  = h;
    h = f2bf(my); l = f2bf(my - bf2f(h)); e[5] = h; e[6] = l; e[7]  = h;
    h = f2bf(mz); l = f2bf(mz - bf2f(h)); e[8] = h; e[9] = l; e[10] = h;
    #pragma unroll
    for (int j = 0; j < 16; ++j) tbl[s * 16 + j] = e[j];
    tblf[s] = make_float4(mx, my, mz, s2);
}

// ===== main: pooled-sample threshold -> 32x32 MFMA sweep -> parallel exact refine ====
__global__ __launch_bounds__(NT, 8) void knn_mfma(
    const float* __restrict__ qc, const float* __restrict__ sf,
    const unsigned short* __restrict__ tbl, const float4* __restrict__ tblf,
    float* __restrict__ out)
{
    __shared__ unsigned short s_qvec[QPB][16];   // query K-vectors (1 KB)
    __shared__ float4 s_q[QPB];                  // qx,qy,qz,q2 (f32, refine)
    __shared__ float  s_samp[8][KNN][QPB + 1];   // padded: pool reads 2-way max
    __shared__ float  s_thrq[QPB];               // pooled threshold (+MARGIN)
    __shared__ int    s_cnt[QPB];
    __shared__ int    s_cand[QPB][CAP];          // 16 KB
    __shared__ int    s_idx[QPB][KNN];
    __shared__ float  s_w[QPB][KNN];

    const int tid = threadIdx.x;

    // XCD swizzle: batch b -> XCD pair {2b,2b+1}; bijective over 1024 blocks.
    const int p   = blockIdx.x;
    const int b   = (p >> 1) & 3;
    const int sub = ((p >> 3) << 1) | (p & 1);   // 0..255
    const int q0  = b * NQ + sub * QPB;

    // ---- stage query K-vectors + f32 coords ----
    if (tid < QPB) {
        const float* qp = qc + (size_t)(q0 + tid) * 3;
        const float qx = qp[0], qy = qp[1], qz = qp[2];
        const float q2 = __fmaf_rn(qx, qx, __fmaf_rn(qy, qy, __fmul_rn(qz, qz)));
        s_q[tid] = make_float4(qx, qy, qz, q2);
        #pragma unroll
        for (int j = 11; j < 16; ++j) s_qvec[tid][j] = 0;
        const unsigned short one = f2bf(1.0f);
        unsigned short h, l;
        s_qvec[tid][0] = one; s_qvec[tid][1] = one;
        h = f2bf(qx); l = f2bf(qx - bf2f(h));
        s_qvec[tid][2] = h; s_qvec[tid][3] = h; s_qvec[tid][4]  = l;
        h = f2bf(qy); l = f2bf(qy - bf2f(h));
        s_qvec[tid][5] = h; s_qvec[tid][6] = h; s_qvec[tid][7]  = l;
        h = f2bf(qz); l = f2bf(qz - bf2f(h));
        s_qvec[tid][8] = h; s_qvec[tid][9] = h; s_qvec[tid][10] = l;
        s_cnt[tid] = 0;
    }
    __syncthreads();

    const int wid  = tid >> 6;        // wave 0..7 -> tiles [wid*16, wid*16+16)
    const int lane = tid & 63;
    const int ln31 = lane & 31;       // A row within tile / B query col
    const int kc   = lane >> 5;       // k-chunk 0..1 (A/B k = 8*kc + j)
    const int t0   = wid * TPW;

    // B fragment: col = lane&31 (query), k = 8*(lane>>5)+j  [r13-verified]
    const bf16x8 bfrag = *reinterpret_cast<const bf16x8*>(&s_qvec[ln31][kc * 8]);
    const f32x16 zero = {};

    // A fragment source: row = lane&31 (sensor in tile), k = 8*(lane>>5)+j
    const unsigned short* abase = tbl + ((size_t)ln31 * 16 + kc * 8);

    // ---- pass S: top-8 over 4 sampled tiles (128 sensors/query/wave; 1024 pooled) ----
    float kd[KNN];
    #pragma unroll
    for (int j = 0; j < KNN; ++j) kd[j] = 3.4e38f;

    #pragma unroll
    for (int ts = 0; ts < SAMPT; ++ts) {
        const int t = t0 + ts * (TPW / SAMPT);
        const bf16x8 a = *reinterpret_cast<const bf16x8*>(abase + (size_t)t * 512);
        const f32x16 d = __builtin_amdgcn_mfma_f32_32x32x16_bf16(a, bfrag, zero, 0, 0, 0);
        #pragma unroll
        for (int r = 0; r < 16; ++r) {
            const float x = d[r];
            if (x < kd[KNN-1]) {     // insert is a no-op unless x beats the 8th
                const float nk0 = fminf(kd[0], x);
                #pragma unroll
                for (int j = KNN - 1; j >= 1; --j) kd[j] = med3(kd[j-1], kd[j], x);
                kd[0] = nk0;
            }
        }
    }

    // ---- tournament over the 2 lanes holding this query (xor 32): record top-8 ----
    float smp[KNN];
    #pragma unroll
    for (int r = 0; r < KNN; ++r) {
        float m = fminf(kd[0], __shfl_xor(kd[0], 32, 64));
        const bool pop = (kd[0] == m);   // tie over-pop only RAISES values (safe)
        #pragma unroll
        for (int j = 0; j < KNN - 1; ++j) kd[j] = pop ? kd[j+1] : kd[j];
        kd[KNN-1] = pop ? 3.4e38f : kd[KNN-1];
        smp[r] = m;
    }
    if (lane < 32) {
        #pragma unroll
        for (int r = 0; r < KNN; ++r) s_samp[wid][r][ln31] = smp[r];  // stride-1
    }
    __syncthreads();

    // ---- parallel pool: subgroup (wid,sg) pools query qr = wid*4+sg ----
    // 64 sample values; lane li holds 4 sorted; 8-round 16-lane pop-tournament
    // -> pooled sample-8th (exact: global-top-8 samples lie in per-wave top-8s).
    {
        const int sg = lane >> 4;
        const int li = lane & 15;
        const int qr = wid * 4 + sg;
        const int v0 = li * 4;
        const float x0 = s_samp[(v0+0) >> 3][(v0+0) & 7][qr];
        const float x1 = s_samp[(v0+1) >> 3][(v0+1) & 7][qr];
        const float x2 = s_samp[(v0+2) >> 3][(v0+2) & 7][qr];
        const float x3 = s_samp[(v0+3) >> 3][(v0+3) & 7][qr];
        // sort-4 network (ascending)
        const float a0 = fminf(x0, x1), a1 = fmaxf(x0, x1);
        const float a2 = fminf(x2, x3), a3 = fmaxf(x2, x3);
        const float b0 = fminf(a0, a2), b2 = fmaxf(a0, a2);
        const float b1 = fminf(a1, a3), b3 = fmaxf(a1, a3);
        float l0 = b0, l1 = fminf(b1, b2), l2 = fmaxf(b1, b2), l3 = b3;
        float m = 3.4e38f;
        #pragma unroll
        for (int r = 0; r < KNN; ++r) {
            m = l0;
            m = fminf(m, __shfl_xor(m, 1, 64));
            m = fminf(m, __shfl_xor(m, 2, 64));
            m = fminf(m, __shfl_xor(m, 4, 64));
            m = fminf(m, __shfl_xor(m, 8, 64));
            const bool pop = (l0 == m);
            l0 = pop ? l1 : l0;
            l1 = pop ? l2 : l1;
            l2 = pop ? l3 : l2;
            l3 = pop ? 3.4e38f : l3;
        }
        if (li == 0) s_thrq[qr] = m + MARGIN;   // superset threshold (proof as r8)
    }
    __syncthreads();

    const float thr_eff = s_thrq[ln31];

    // ---- pass C: sweep this wave's 16 tiles (A-load pipelined, batched atomic) ----
    {
        bf16x8 a = *reinterpret_cast<const bf16x8*>(abase + (size_t)t0 * 512);
        #pragma unroll 2
        for (int tt = 0; tt < TPW; ++tt) {
            const int t = t0 + tt;
            bf16x8 an = a;
            if (tt + 1 < TPW)
                an = *reinterpret_cast<const bf16x8*>(abase + (size_t)(t + 1) * 512);
            const f32x16 d = __builtin_amdgcn_mfma_f32_32x32x16_bf16(a, bfrag, zero, 0, 0, 0);
            bool h[16];
            int n = 0;
            #pragma unroll
            for (int r = 0; r < 16; ++r) { h[r] = d[r] <= thr_eff; n += (int)h[r]; }
            if (n) {
                int pos = atomicAdd(&s_cnt[ln31], n);   // one atomic per lane-tile
                #pragma unroll
                for (int r = 0; r < 16; ++r) {
                    if (h[r]) {
                        // C row = (r&3) + 8*(r>>2) + 4*(lane>>5)  [r13-verified]
                        const int row = (r & 3) + 8 * (r >> 2) + 4 * kc;
                        if (pos < CAP) s_cand[ln31][pos] = t * 32 + row;
                        ++pos;
                    }
                }
            }
            a = an;
        }
    }
    __syncthreads();

    // ---- parallel exact refine: wave wid -> queries wid*4..+3 ----
    // 16 lanes per query split candidates; per-lane sorted u64 top-8;
    // 16-lane u64 pop-tournament -> exact top-8 (keys unique -> one pop).
    {
        const int sg = lane >> 4;            // subgroup 0..3
        const int li = lane & 15;            // lane within subgroup
        const int qr = wid * 4 + sg;         // query refined by this subgroup (0..31)
        const int cnt0 = s_cnt[qr];
        const float qx = s_q[qr].x, qy = s_q[qr].y, qz = s_q[qr].z, q2 = s_q[qr].w;

        u64 kb[KNN];
        #pragma unroll
        for (int j = 0; j < KNN; ++j) kb[j] = ~0ull;

        if (cnt0 <= CAP) {
            for (int i = li; i < cnt0; i += 16) {
                const int sid = s_cand[qr][i];
                const float4 m = tblf[sid];
                const float x  = __fmaf_rn(qx, m.x,
                                 __fmaf_rn(qy, m.y, __fmaf_rn(qz, m.z, m.w)));
                const float d2 = fmaxf(__fadd_rn(x, q2), 0.0f);
                u64 cur = ((u64)__float_as_uint(d2) << 32) | (unsigned)sid;
                #pragma unroll
                for (int j = 0; j < KNN; ++j) {
                    const u64 lo = kb[j] < cur ? kb[j] : cur;
                    const u64 hi = kb[j] < cur ? cur : kb[j];
                    kb[j] = lo; cur = hi;
                }
            }
        } else {
            // safety net (~10 sigma): exact full scan, split over 16 lanes
            for (int sid = li; sid < NS; sid += 16) {
                const float4 m = tblf[sid];
                const float x  = __fmaf_rn(qx, m.x,
                                 __fmaf_rn(qy, m.y, __fmaf_rn(qz, m.z, m.w)));
                const float d2 = fmaxf(__fadd_rn(x, q2), 0.0f);
                u64 cur = ((u64)__float_as_uint(d2) << 32) | (unsigned)sid;
                #pragma unroll
                for (int j = 0; j < KNN; ++j) {
                    const u64 lo = kb[j] < cur ? kb[j] : cur;
                    const u64 hi = kb[j] < cur ? cur : kb[j];
                    kb[j] = lo; cur = hi;
                }
            }
        }

        u64 sel = ~0ull;
        #pragma unroll
        for (int r = 0; r < KNN; ++r) {
            u64 v = kb[0];
            #pragma unroll
            for (int m = 1; m <= 8; m <<= 1) {
                const u64 o = __shfl_xor(v, m, 64);   // stays within 16-lane group
                v = o < v ? o : v;
            }
            const bool pop = (kb[0] == v);
            #pragma unroll
            for (int j = 0; j < KNN - 1; ++j) kb[j] = pop ? kb[j+1] : kb[j];
            kb[KNN-1] = pop ? ~0ull : kb[KNN-1];
            if (li == r) sel = v;
        }

        // weights on lanes 0..7 of each subgroup (xor 1,2,4 stays within 0..7)
        const float d2v = __uint_as_float((unsigned)(sel >> 32));
        const int   idx = (int)(unsigned)(sel & 0xFFFFFFFFu);
        const float w   = 1.0f / (sqrtf(d2v) + 1e-8f);
        float ws = w;
        ws += __shfl_xor(ws, 1, 64);
        ws += __shfl_xor(ws, 2, 64);
        ws += __shfl_xor(ws, 4, 64);
        if (li < KNN) {
            s_idx[qr][li] = idx;
            s_w[qr][li]   = w / ws;
        }
    }
    __syncthreads();

    // ---- gather: wave wid -> queries wid*4..+3; 64 lanes x float4 ----
    const float* fb = sf + (size_t)b * NS * FDIM;
    #pragma unroll 1
    for (int jq = 0; jq < QPB / 8; ++jq) {
        const int ql = wid * (QPB / 8) + jq;
        float4 acc = {0.f, 0.f, 0.f, 0.f};
        #pragma unroll
        for (int kk = 0; kk < KNN; ++kk) {
            const int   sid = s_idx[ql][kk];
            const float wk  = s_w[ql][kk];
            const float4 v = ((const float4*)(fb + (size_t)sid * FDIM))[lane];
            acc.x += wk * v.x; acc.y += wk * v.y;
            acc.z += wk * v.z; acc.w += wk * v.w;
        }
        ((float4*)(out + (size_t)(q0 + ql) * FDIM))[lane] = acc;
    }
}

// ================= fallback (round-6 kernel) if workspace too small =================
#define FG    16
#define FQL   2
#define FNT   512
#define FGRP  (FNT / FG)
#define FQPB  (FGRP * FQL)
#define FSCAN (NS / FG)
#define FCAP  16

#define FKEYX(m, qq) __fmaf_rn(fqx[qq], (m).x, \
                     __fmaf_rn(fqy[qq], (m).y, \
                     __fmaf_rn(fqz[qq], (m).z, (m).w)))

__global__ __launch_bounds__(FNT, 4) void idw_fallback(
    const float* __restrict__ qc, const float* __restrict__ sc,
    const float* __restrict__ sf, float* __restrict__ out)
{
    __shared__ float4 s_m[NS];
    __shared__ u64    s_items[FQPB * FCAP];
    __shared__ int    s_cnt[FQPB];
    __shared__ int    s_idx[FQPB * KNN];
    __shared__ float  s_w[FQPB * KNN];

    const int tid = threadIdx.x;
    const int p   = blockIdx.x;
    const int b   = (p >> 1) & 3;
    const int sub = ((p >> 3) << 1) | (p & 1);
    const int q0  = b * NQ + sub * FQPB;

    for (int s = tid; s < NS; s += FNT) {
        const float sx = sc[3*s+0], sy = sc[3*s+1], sz = sc[3*s+2];
        const float s2 = __fmaf_rn(sx, sx, __fmaf_rn(sy, sy, __fmul_rn(sz, sz)));
        s_m[s] = make_float4(-2.0f*sx, -2.0f*sy, -2.0f*sz, s2);
    }
    if (tid < FQPB) s_cnt[tid] = 0;
    __syncthreads();

    const int g = tid >> 4, l = tid & 15;
    float fqx[FQL], fqy[FQL], fqz[FQL], fq2[FQL];
    #pragma unroll
    for (int qq = 0; qq < FQL; ++qq) {
        const float* qp = qc + (size_t)(q0 + g * FQL + qq) * 3;
        fqx[qq] = qp[0]; fqy[qq] = qp[1]; fqz[qq] = qp[2];
        fq2[qq] = __fmaf_rn(fqx[qq], fqx[qq],
                  __fmaf_rn(fqy[qq], fqy[qq], __fmul_rn(fqz[qq], fqz[qq])));
    }

    float kd[FQL][KNN];
    #pragma unroll
    for (int qq = 0; qq < FQL; ++qq)
        #pragma unroll
        for (int j = 0; j < KNN; ++j) kd[qq][j] = 3.4e38f;

    #pragma unroll 2
    for (int t = 0; t < FSCAN; ++t) {
        const float4 m = s_m[t * FG + l];
        #pragma unroll
        for (int qq = 0; qq < FQL; ++qq) {
            const float x = FKEYX(m, qq);
            const float nk0 = fminf(kd[qq][0], x);
            #pragma unroll
            for (int j = KNN - 1; j >= 1; --j)
                kd[qq][j] = med3(kd[qq][j-1], kd[qq][j], x);
            kd[qq][0] = nk0;
        }
    }

    float thr[FQL];
    #pragma unroll
    for (int qq = 0; qq < FQL; ++qq) {
        float thv = 3.4e38f;
        #pragma unroll
        for (int r = 0; r < KNN; ++r) {
            float m = kd[qq][0];
            m = fminf(m, __shfl_xor(m, 1, 64));
            m = fminf(m, __shfl_xor(m, 2, 64));
            m = fminf(m, __shfl_xor(m, 4, 64));
            m = fminf(m, __shfl_xor(m, 8, 64));
            const bool pop = (kd[qq][0] == m);
            #pragma unroll
            for (int j = 0; j < KNN - 1; ++j) kd[qq][j] = pop ? kd[qq][j+1] : kd[qq][j];
            kd[qq][KNN-1] = pop ? 3.4e38f : kd[qq][KNN-1];
            thv = m;
        }
        thr[qq] = thv;
    }

    #pragma unroll 2
    for (int t = 0; t < FSCAN; ++t) {
        const int s = t * FG + l;
        const float4 m = s_m[s];
        #pragma unroll
        for (int qq = 0; qq < FQL; ++qq) {
            const float x = FKEYX(m, qq);
            if (x <= thr[qq]) {
                const float dc = fmaxf(__fadd_rn(x, fq2[qq]), 0.0f);
                const u64 key = ((u64)__float_as_uint(dc) << 32) | (unsigned)s;
                const int qid = g * FQL + qq;
                const int pos = atomicAdd(&s_cnt[qid], 1);
                if (pos < FCAP) s_items[qid * FCAP + pos] = key;
            }
        }
    }
    __syncthreads();

    if (l < FQL) {
        const int qid = g * FQL + l;
        int cnt = s_cnt[qid];
        if (cnt > KNN) {
            cnt = cnt < FCAP ? cnt : FCAP;
            u64 best[KNN];
            #pragma unroll
            for (int j = 0; j < KNN; ++j) best[j] = ~0ull;
            for (int i = 0; i < cnt; ++i) {
                u64 cur = s_items[qid * FCAP + i];
                #pragma unroll
                for (int j = 0; j < KNN; ++j) {
                    const u64 lo = best[j] < cur ? best[j] : cur;
                    const u64 hi = best[j] < cur ? cur : best[j];
                    best[j] = lo; cur = hi;
                }
            }
            #pragma unroll
            for (int j = 0; j < KNN; ++j) s_items[qid * FCAP + j] = best[j];
        }
    }
    __syncthreads();

    {
        const int qq  = l >> 3;
        const int k   = l & 7;
        const int qid = g * FQL + qq;
        const u64 key = s_items[qid * FCAP + k];
        const float d2v = __uint_as_float((unsigned)(key >> 32));
        const int   idx = (int)(unsigned)(key & 0xFFFFFFFFu);
        const float w   = 1.0f / (sqrtf(d2v) + 1e-8f);
        float ws = w;
        ws += __shfl_xor(ws, 1, 64);
        ws += __shfl_xor(ws, 2, 64);
        ws += __shfl_xor(ws, 4, 64);
        s_idx[qid * KNN + k] = idx;
        s_w  [qid * KNN + k] = w / ws;
    }
    __syncthreads();

    const int wave = tid >> 6, lane = tid & 63;
    const float* fb = sf + (size_t)b * NS * FDIM;
    #pragma unroll 1
    for (int j = 0; j < FQPB / 8; ++j) {
        const int ql = wave * (FQPB / 8) + j;
        float4 acc = {0.f, 0.f, 0.f, 0.f};
        #pragma unroll
        for (int kk = 0; kk < KNN; ++kk) {
            const int   sid = s_idx[ql * KNN + kk];
            const float wk  = s_w  [ql * KNN + kk];
            const float4 v = ((const float4*)(fb + (size_t)sid * FDIM))[lane];
            acc.x += wk * v.x; acc.y += wk * v.y;
            acc.z += wk * v.z; acc.w += wk * v.w;
        }
        ((float4*)(out + (size_t)(q0 + ql) * FDIM))[lane] = acc;
    }
}

extern "C" void kernel_launch(void* const* d_in, const int* in_sizes, int n_in,
                              void* d_out, int out_size, void* d_ws, size_t ws_size,
                              hipStream_t stream) {
    const float* qc = (const float*)d_in[0];   // query_coords  (4,8192,3)
    const float* sc = (const float*)d_in[1];   // sensor_coords (4096,3)
    const float* sf = (const float*)d_in[2];   // sensor_features (4,4096,256)
    float* out = (float*)d_out;                // (4,8192,256)

    if (ws_size >= (size_t)WS_NEED) {
        unsigned short* tbl  = (unsigned short*)d_ws;
        float4*         tblf = (float4*)((char*)d_ws + WS_TBLF);
        build_tbl<<<NS / 256, 256, 0, stream>>>(sc, tbl, tblf);
        knn_mfma<<<(BB * NQ) / QPB, NT, 0, stream>>>(qc, sf, tbl, tblf, out);
    } else {
        idw_fallback<<<(BB * NQ) / FQPB, FNT, 0, stream>>>(qc, sc, sf, out);
    }
}